// Round 4
// baseline (475.120 us; speedup 1.0000x reference)
//
#include <hip/hip_runtime.h>
#include <hip/hip_bf16.h>

#define N_NODES 8192
#define IN_F    256
#define OUT_F   128
#define ALPHA_S 0.2f

typedef __attribute__((ext_vector_type(8))) short  short8;   // 8 bf16
typedef __attribute__((ext_vector_type(4))) float  floatx4;  // MFMA acc
typedef __attribute__((ext_vector_type(4))) int    intx4;
typedef __attribute__((ext_vector_type(4))) float  fx4;

static __device__ __forceinline__ float bf2f(short s) {
    union { unsigned int i; float f; } u;
    u.i = ((unsigned int)(unsigned short)s) << 16;
    return u.f;
}
static __device__ __forceinline__ short f2bf(float f) {
    union { float f; unsigned int i; } u; u.f = f;
    unsigned int r = u.i + 0x7FFFu + ((u.i >> 16) & 1u);  // RNE
    return (short)(r >> 16);
}

// ---------------------------------------------------------------------------
// Dtype detector (robustness): bf16 data -> word bits [14:7] are a bf16
// exponent in [100,140] for N(0,1); fp32 data -> uniform mantissa bits.
// R1/R2 evidence says inputs are fp32, but keep the guard.
// ---------------------------------------------------------------------------
__global__ void k_detect(const unsigned int* __restrict__ hw, int* __restrict__ flag) {
    const int lane = threadIdx.x;
    unsigned int w = hw[lane * 31];
    int e = (w >> 7) & 0xFF;
    unsigned long long b = __ballot(e >= 100 && e <= 140);
    if (lane == 0) *flag = (__popcll(b) >= 40) ? 1 : 0;   // 1 = bf16
}

static __device__ __forceinline__ void load8(const short* p, float* o) {
    short8 v = *(const short8*)p;
#pragma unroll
    for (int j = 0; j < 8; ++j) o[j] = bf2f(v[j]);
}
static __device__ __forceinline__ void load8(const float* p, float* o) {
    float4 v0 = *(const float4*)p;
    float4 v1 = *(const float4*)(p + 4);
    o[0] = v0.x; o[1] = v0.y; o[2] = v0.z; o[3] = v0.w;
    o[4] = v1.x; o[5] = v1.y; o[6] = v1.z; o[7] = v1.w;
}
static __device__ __forceinline__ float to_f(short s)  { return bf2f(s); }
static __device__ __forceinline__ float to_f(float f)  { return f; }

// ---------------------------------------------------------------------------
// Phase 1: Wh = h @ W (fp32 accum), store WhT bf16 [OUT_F][N_NODES],
//          src = Wh@a1, dst = Wh@a2 (fp32). 256 blocks x 512 threads.
// ---------------------------------------------------------------------------
template<typename T>
static __device__ void wh_impl(const T* __restrict__ h, const T* __restrict__ W,
                               const T* __restrict__ a,
                               short* __restrict__ WhT, float* __restrict__ src,
                               float* __restrict__ dst,
                               float* h_tile, short* wh_t, int t, int r_base)
{
    {   // stage 32x256 h tile to fp32 LDS
        const T* g = h + (size_t)r_base * IN_F;
        float tmp[8];
        load8(g + t * 16, tmp);
#pragma unroll
        for (int j = 0; j < 8; ++j) h_tile[t * 16 + j] = tmp[j];
        load8(g + t * 16 + 8, tmp);
#pragma unroll
        for (int j = 0; j < 8; ++j) h_tile[t * 16 + 8 + j] = tmp[j];
    }
    __syncthreads();

    const int r0   = t >> 4;        // 0..31
    const int fgrp = t & 15;
    const int f0   = fgrp * 8;

    float acc[8];
#pragma unroll
    for (int j = 0; j < 8; ++j) acc[j] = 0.f;

#pragma unroll 4
    for (int k = 0; k < IN_F; ++k) {
        float hf = h_tile[r0 * IN_F + k];
        float wv[8];
        load8(W + (size_t)k * OUT_F + f0, wv);
#pragma unroll
        for (int j = 0; j < 8; ++j)
            acc[j] = fmaf(hf, wv[j], acc[j]);
    }

    float sp = 0.f, dp = 0.f;
#pragma unroll
    for (int j = 0; j < 8; ++j) {
        sp = fmaf(acc[j], to_f(a[f0 + j]), sp);
        dp = fmaf(acc[j], to_f(a[OUT_F + f0 + j]), dp);
    }
#pragma unroll
    for (int m = 1; m < 16; m <<= 1) {
        sp += __shfl_xor(sp, m, 64);
        dp += __shfl_xor(dp, m, 64);
    }
    if (fgrp == 0) {
        src[r_base + r0] = sp;
        dst[r_base + r0] = dp;
    }

    // transpose via LDS -> WhT[f][node], 16B chunks
#pragma unroll
    for (int j = 0; j < 8; ++j)
        wh_t[(f0 + j) * 32 + r0] = f2bf(acc[j]);
    __syncthreads();
    {
        const int f    = t >> 2;    // 0..127
        const int half = t & 3;
        *(short8*)(WhT + (size_t)f * N_NODES + r_base + half * 8) =
            *(const short8*)&wh_t[f * 32 + half * 8];
    }
}

__global__ __launch_bounds__(512) void k_wh(
    const void* __restrict__ h, const void* __restrict__ W, const void* __restrict__ a,
    const int* __restrict__ flag,
    short* __restrict__ WhT, float* __restrict__ src, float* __restrict__ dst)
{
    __shared__ float h_tile[32 * IN_F];   // 32 KB
    __shared__ short wh_t[OUT_F * 32];    // 8 KB
    const int t = threadIdx.x;
    const int r_base = blockIdx.x * 32;
    if (*flag)
        wh_impl<short>((const short*)h, (const short*)W, (const short*)a,
                       WhT, src, dst, h_tile, wh_t, t, r_base);
    else
        wh_impl<float>((const float*)h, (const float*)W, (const float*)a,
                       WhT, src, dst, h_tile, wh_t, t, r_base);
}

// ---------------------------------------------------------------------------
// Phase 2: fused mask + exp + (P @ Wh) / rowsum + ELU, MFMA, fp32 out.
// 256 blocks x 512 threads (8 waves). BM=32 rows, BK=128 j per iteration.
// ---------------------------------------------------------------------------
#define BM 32
#define BK 128
#define WPAD (BK + 8)      // LDS row stride in shorts, breaks pow2
#define NIT (N_NODES / BK) // 64

__global__ __launch_bounds__(512) void k_attn(
    const int*   __restrict__ adj,   // [N][N] int32
    const short* __restrict__ WhT,   // [OUT_F][N] bf16
    const float* __restrict__ src,
    const float* __restrict__ dstv,
    float* __restrict__ out)         // [N][OUT_F] fp32
{
    __shared__ short wbuf[2][BM * WPAD];  // 2 x 8.5 KB
    __shared__ float denom_s[BM];

    const int t    = threadIdx.x;
    const int lane = t & 63;
    const int wave = t >> 6;          // 0..7
    const int r0   = blockIdx.x * BM;

    // staging: thread -> (row sm, 8 consecutive j at sk0)
    const int sm  = t >> 4;           // 0..31
    const int sk0 = (t & 15) * 8;     // 0..120
    const float srow = src[r0 + sm];
    const size_t adj_base = (size_t)(r0 + sm) * N_NODES;

    // mfma mapping
    const int ln15 = lane & 15;
    const int q    = lane >> 4;       // 0..3
    const int f0   = wave * 16;
    const short* bbase = WhT + (size_t)(f0 + ln15) * N_NODES + q * 8;

    floatx4 acc0 = {0.f, 0.f, 0.f, 0.f};
    floatx4 acc1 = {0.f, 0.f, 0.f, 0.f};
    floatx4 dac0 = {0.f, 0.f, 0.f, 0.f};
    floatx4 dac1 = {0.f, 0.f, 0.f, 0.f};
    short8 ones;
#pragma unroll
    for (int j = 0; j < 8; ++j) ones[j] = (short)0x3F80;  // bf16 1.0

    auto stage = [&](int it, int buf) {
        const size_t j0 = (size_t)it * BK;
        intx4 m0 = *(const intx4*)(adj + adj_base + j0 + sk0);
        intx4 m1 = *(const intx4*)(adj + adj_base + j0 + sk0 + 4);
        fx4  d0  = *(const fx4*)(dstv + j0 + sk0);
        fx4  d1  = *(const fx4*)(dstv + j0 + sk0 + 4);
        short8 wv;
#pragma unroll
        for (int e = 0; e < 4; ++e) {
            float x = srow + d0[e];
            float l = fmaxf(x, ALPHA_S * x);
            wv[e] = (m0[e] > 0) ? f2bf(__expf(l)) : (short)0;
        }
#pragma unroll
        for (int e = 0; e < 4; ++e) {
            float x = srow + d1[e];
            float l = fmaxf(x, ALPHA_S * x);
            wv[4 + e] = (m1[e] > 0) ? f2bf(__expf(l)) : (short)0;
        }
        *(short8*)&wbuf[buf][sm * WPAD + sk0] = wv;
    };

    auto compute = [&](int it, int buf) {
        const int j0 = it * BK;
        const short* ab = &wbuf[buf][ln15 * WPAD + q * 8];
        const short* bb = bbase + j0;
#pragma unroll
        for (int ks = 0; ks < 4; ++ks) {
            short8 afr0 = *(const short8*)(ab + ks * 32);
            short8 afr1 = *(const short8*)(ab + 16 * WPAD + ks * 32);
            short8 bfr  = *(const short8*)(bb + ks * 32);
            acc0 = __builtin_amdgcn_mfma_f32_16x16x32_bf16(afr0, bfr, acc0, 0, 0, 0);
            acc1 = __builtin_amdgcn_mfma_f32_16x16x32_bf16(afr1, bfr, acc1, 0, 0, 0);
            if (wave == 0) {
                dac0 = __builtin_amdgcn_mfma_f32_16x16x32_bf16(afr0, ones, dac0, 0, 0, 0);
                dac1 = __builtin_amdgcn_mfma_f32_16x16x32_bf16(afr1, ones, dac1, 0, 0, 0);
            }
        }
    };

    stage(0, 0);
    for (int it = 0; it < NIT; ++it) {
        const int p = it & 1;
        __syncthreads();
        if (it + 1 < NIT) stage(it + 1, p ^ 1);
        compute(it, p);
    }

    // epilogue: share denominators, divide, ELU, fp32 store
    if (wave == 0 && ln15 == 0) {
#pragma unroll
        for (int r = 0; r < 4; ++r) {
            denom_s[q * 4 + r]      = dac0[r];
            denom_s[16 + q * 4 + r] = dac1[r];
        }
    }
    __syncthreads();
#pragma unroll
    for (int r = 0; r < 4; ++r) {
        const int row0 = q * 4 + r;
        float v0 = acc0[r] / denom_s[row0];
        v0 = v0 > 0.f ? v0 : (__expf(v0) - 1.f);
        out[(size_t)(r0 + row0) * OUT_F + f0 + ln15] = v0;

        const int row1 = 16 + q * 4 + r;
        float v1 = acc1[r] / denom_s[row1];
        v1 = v1 > 0.f ? v1 : (__expf(v1) - 1.f);
        out[(size_t)(r0 + row1) * OUT_F + f0 + ln15] = v1;
    }
}

// ---------------------------------------------------------------------------
extern "C" void kernel_launch(void* const* d_in, const int* in_sizes, int n_in,
                              void* d_out, int out_size, void* d_ws, size_t ws_size,
                              hipStream_t stream) {
    const void* h   = d_in[0];                  // [8192][256] fp32
    const int*  adj = (const int*)d_in[1];      // int32 [8192][8192]
    const void* W   = d_in[2];                  // [256][128] fp32
    const void* a   = d_in[3];                  // [256] fp32
    float* out = (float*)d_out;                 // fp32 [8192][128]

    char* ws    = (char*)d_ws;
    int*   flag = (int*)ws;
    short* WhT  = (short*)(ws + 256);                               // 2 MB
    float* src  = (float*)(ws + 256 + (size_t)OUT_F * N_NODES * 2); // 32 KB
    float* dst  = src + N_NODES;                                    // 32 KB

    k_detect<<<1, 64, 0, stream>>>((const unsigned int*)h, flag);
    k_wh<<<256, 512, 0, stream>>>(h, W, a, flag, WhT, src, dst);
    k_attn<<<256, 512, 0, stream>>>(adj, WhT, src, dst, out);
}

// Round 5
// 406.818 us; speedup vs baseline: 1.1679x; 1.1679x over previous
//
#include <hip/hip_runtime.h>

#define N_NODES 8192
#define IN_F    256
#define OUT_F   128
#define ALPHA_S 0.2f

typedef __attribute__((ext_vector_type(8))) short  short8;
typedef __attribute__((ext_vector_type(4))) short  short4v;
typedef __attribute__((ext_vector_type(4))) float  floatx4;
typedef __attribute__((ext_vector_type(4))) int    intx4;
typedef __attribute__((ext_vector_type(4))) float  fx4;

static __device__ __forceinline__ short f2bf(float f) {
    union { float f; unsigned int i; } u; u.f = f;
    unsigned int r = u.i + 0x7FFFu + ((u.i >> 16) & 1u);  // RNE
    return (short)(r >> 16);
}

// ---------------------------------------------------------------------------
// k_zero: zero numerator (d_out, 1048576 floats) + denominator (ws, 8192 floats)
// ---------------------------------------------------------------------------
__global__ void k_zero(float4* __restrict__ out4, float4* __restrict__ den4) {
    const int i = blockIdx.x * 256 + threadIdx.x;   // grid 1032 -> 264192 exact
    float4 z; z.x = 0.f; z.y = 0.f; z.z = 0.f; z.w = 0.f;
    if (i < 262144) out4[i] = z;
    else if (i < 264192) den4[i - 262144] = z;
}

// ---------------------------------------------------------------------------
// k_wh: Wh = h @ W via bf16 MFMA -> WhT bf16 [OUT_F][N_NODES].
//       src/dst computed fp32-exact: q1=W@a1, q2=W@a2 folded into W staging,
//       then src_i = h_i . q1 (fp32). 256 blocks x 512 threads, 32 rows/block.
// LDS: Wt 67.6KB + htile 16.9KB + q 2KB + wh_t 10.2KB = ~97KB (1 block/CU, fine)
// ---------------------------------------------------------------------------
__global__ __launch_bounds__(512) void k_wh(
    const float* __restrict__ h,    // [N][IN_F] fp32
    const float* __restrict__ W,    // [IN_F][OUT_F] fp32
    const float* __restrict__ a,    // [2*OUT_F] fp32
    short* __restrict__ WhT,        // [OUT_F][N] bf16
    float* __restrict__ src,
    float* __restrict__ dst)
{
    __shared__ short Wt[OUT_F][IN_F + 8];     // [f][k], pad 8 -> conflict-free frags
    __shared__ short htile[32][IN_F + 8];     // [row][k] bf16
    __shared__ float q1s[IN_F], q2s[IN_F];
    __shared__ short wh_t[OUT_F][40];         // [f][row], stride 40 (16B-aligned chunks)

    const int t      = threadIdx.x;
    const int lane   = t & 63;
    const int wave   = t >> 6;
    const int r_base = blockIdx.x * 32;

    // ---- stage W -> Wt (bf16 transposed) and q1/q2 = W@a1, W@a2 (fp32)
#pragma unroll
    for (int rep = 0; rep < 4; ++rep) {
        const int idx = rep * 8192 + t * 16;  // 16 consecutive f of one k
        const int k   = idx >> 7;
        const int f   = idx & 127;
        fx4 w0 = *(const fx4*)(W + idx);
        fx4 w1 = *(const fx4*)(W + idx + 4);
        fx4 w2 = *(const fx4*)(W + idx + 8);
        fx4 w3 = *(const fx4*)(W + idx + 12);
        fx4 a10 = *(const fx4*)(a + f);
        fx4 a11 = *(const fx4*)(a + f + 4);
        fx4 a12 = *(const fx4*)(a + f + 8);
        fx4 a13 = *(const fx4*)(a + f + 12);
        fx4 a20 = *(const fx4*)(a + OUT_F + f);
        fx4 a21 = *(const fx4*)(a + OUT_F + f + 4);
        fx4 a22 = *(const fx4*)(a + OUT_F + f + 8);
        fx4 a23 = *(const fx4*)(a + OUT_F + f + 12);
        float p1 = 0.f, p2 = 0.f;
#pragma unroll
        for (int e = 0; e < 4; ++e) {
            p1 = fmaf(w0[e], a10[e], p1); p2 = fmaf(w0[e], a20[e], p2);
            p1 = fmaf(w1[e], a11[e], p1); p2 = fmaf(w1[e], a21[e], p2);
            p1 = fmaf(w2[e], a12[e], p1); p2 = fmaf(w2[e], a22[e], p2);
            p1 = fmaf(w3[e], a13[e], p1); p2 = fmaf(w3[e], a23[e], p2);
        }
        // transpose-scatter bf16 into Wt
#pragma unroll
        for (int e = 0; e < 4; ++e) {
            Wt[f + e][k]      = f2bf(w0[e]);
            Wt[f + 4 + e][k]  = f2bf(w1[e]);
            Wt[f + 8 + e][k]  = f2bf(w2[e]);
            Wt[f + 12 + e][k] = f2bf(w3[e]);
        }
        // reduce q over the 8 lanes sharing k
#pragma unroll
        for (int m = 1; m < 8; m <<= 1) {
            p1 += __shfl_xor(p1, m, 64);
            p2 += __shfl_xor(p2, m, 64);
        }
        if ((t & 7) == 0) { q1s[k] = p1; q2s[k] = p2; }
    }

    // ---- stage h tile (keep fp32 in regs for src/dst, bf16 to LDS for MFMA)
    const int r0   = t >> 4;          // 0..31
    const int fgrp = t & 15;
    const int k0   = fgrp * 16;
    fx4 h0, h1, h2, h3;
    {
        const float* hp = h + (size_t)(r_base + r0) * IN_F + k0;
        h0 = *(const fx4*)hp; h1 = *(const fx4*)(hp + 4);
        h2 = *(const fx4*)(hp + 8); h3 = *(const fx4*)(hp + 12);
        short8 b0, b1;
#pragma unroll
        for (int e = 0; e < 4; ++e) {
            b0[e]     = f2bf(h0[e]); b0[4 + e] = f2bf(h1[e]);
            b1[e]     = f2bf(h2[e]); b1[4 + e] = f2bf(h3[e]);
        }
        *(short8*)&htile[r0][k0]     = b0;
        *(short8*)&htile[r0][k0 + 8] = b1;
    }
    __syncthreads();

    // ---- src/dst (fp32): dot(h_row, q1/q2), reduce over 16 lanes
    {
        float sp = 0.f, dp = 0.f;
#pragma unroll
        for (int e = 0; e < 4; ++e) {
            sp = fmaf(h0[e], q1s[k0 + e], sp);      dp = fmaf(h0[e], q2s[k0 + e], dp);
            sp = fmaf(h1[e], q1s[k0 + 4 + e], sp);  dp = fmaf(h1[e], q2s[k0 + 4 + e], dp);
            sp = fmaf(h2[e], q1s[k0 + 8 + e], sp);  dp = fmaf(h2[e], q2s[k0 + 8 + e], dp);
            sp = fmaf(h3[e], q1s[k0 + 12 + e], sp); dp = fmaf(h3[e], q2s[k0 + 12 + e], dp);
        }
#pragma unroll
        for (int m = 1; m < 16; m <<= 1) {
            sp += __shfl_xor(sp, m, 64);
            dp += __shfl_xor(dp, m, 64);
        }
        if (fgrp == 0) { src[r_base + r0] = sp; dst[r_base + r0] = dp; }
    }

    // ---- MFMA: wave -> col-tile f0, two row-tiles
    const int ln15 = lane & 15;
    const int q    = lane >> 4;
    const int f0   = wave * 16;
    floatx4 c0 = {0.f, 0.f, 0.f, 0.f};
    floatx4 c1 = {0.f, 0.f, 0.f, 0.f};
#pragma unroll
    for (int s = 0; s < 8; ++s) {
        short8 bf  = *(const short8*)&Wt[f0 + ln15][s * 32 + q * 8];
        short8 a0f = *(const short8*)&htile[ln15][s * 32 + q * 8];
        short8 a1f = *(const short8*)&htile[16 + ln15][s * 32 + q * 8];
        c0 = __builtin_amdgcn_mfma_f32_16x16x32_bf16(a0f, bf, c0, 0, 0, 0);
        c1 = __builtin_amdgcn_mfma_f32_16x16x32_bf16(a1f, bf, c1, 0, 0, 0);
    }
    // ---- C -> wh_t (packed b64 writes), then coalesced WhT store
    {
        short4v p0, p1;
#pragma unroll
        for (int r = 0; r < 4; ++r) { p0[r] = f2bf(c0[r]); p1[r] = f2bf(c1[r]); }
        *(short4v*)&wh_t[f0 + ln15][q * 4]      = p0;
        *(short4v*)&wh_t[f0 + ln15][16 + q * 4] = p1;
    }
    __syncthreads();
    {
        const int f    = t >> 2;     // 0..127
        const int half = t & 3;
        *(short8*)(WhT + (size_t)f * N_NODES + r_base + half * 8) =
            *(const short8*)&wh_t[f][half * 8];
    }
}

// ---------------------------------------------------------------------------
// k_attn: fused mask+exp+(P@Wh) partial sums, 4-way j-split.
// grid 1024 (= 256 row-groups x 4 j-chunks) x 512 threads.
// Register-prefetched staging; one barrier/iter; atomic fp32 partials.
// ---------------------------------------------------------------------------
#define BM 32
#define BK 128
#define WPAD (BK + 8)
#define JCH 2048
#define NIT2 (JCH / BK)   // 16

__global__ __launch_bounds__(512, 4) void k_attn(
    const int*   __restrict__ adj,   // [N][N] int32
    const short* __restrict__ WhT,   // [OUT_F][N] bf16
    const float* __restrict__ src,
    const float* __restrict__ dstv,
    float* __restrict__ numer,       // [N][OUT_F] fp32 (= d_out, pre-zeroed)
    float* __restrict__ denom)       // [N] fp32 (pre-zeroed)
{
    __shared__ short wbuf[2][BM * WPAD];  // 2 x 8.5 KB

    const int t    = threadIdx.x;
    const int lane = t & 63;
    const int wave = t >> 6;
    const int rg   = blockIdx.x >> 2;
    const int jc   = blockIdx.x & 3;
    const int r0   = rg * BM;
    const int jb   = jc * JCH;

    // staging mapping
    const int sm  = t >> 4;
    const int sk0 = (t & 15) * 8;
    const float srow = src[r0 + sm];
    const int*   abase = adj  + (size_t)(r0 + sm) * N_NODES + jb + sk0;
    const float* dbase = dstv + jb + sk0;

    // mfma mapping
    const int ln15 = lane & 15;
    const int q    = lane >> 4;
    const int f0   = wave * 16;
    const short* bbase = WhT + (size_t)(f0 + ln15) * N_NODES + jb + q * 8;

    floatx4 acc0 = {0.f, 0.f, 0.f, 0.f};
    floatx4 acc1 = {0.f, 0.f, 0.f, 0.f};
    floatx4 dac0 = {0.f, 0.f, 0.f, 0.f};
    floatx4 dac1 = {0.f, 0.f, 0.f, 0.f};
    short8 ones;
#pragma unroll
    for (int j = 0; j < 8; ++j) ones[j] = (short)0x3F80;  // bf16 1.0

    // prefetch iter 0
    intx4 m0 = *(const intx4*)abase;
    intx4 m1 = *(const intx4*)(abase + 4);
    fx4   d0 = *(const fx4*)dbase;
    fx4   d1 = *(const fx4*)(dbase + 4);

    for (int it = 0; it < NIT2; ++it) {
        const int p = it & 1;
        // exp weights from already-resident regs -> LDS
        short8 wv;
#pragma unroll
        for (int e = 0; e < 4; ++e) {
            float x = srow + d0[e];
            float l = fmaxf(x, ALPHA_S * x);
            wv[e] = (m0[e] > 0) ? f2bf(__expf(l)) : (short)0;
        }
#pragma unroll
        for (int e = 0; e < 4; ++e) {
            float x = srow + d1[e];
            float l = fmaxf(x, ALPHA_S * x);
            wv[4 + e] = (m1[e] > 0) ? f2bf(__expf(l)) : (short)0;
        }
        *(short8*)&wbuf[p][sm * WPAD + sk0] = wv;
        // issue next iteration's staging loads (vmcnt hidden behind barrier+mfma)
        if (it + 1 < NIT2) {
            const int o = (it + 1) * BK;
            m0 = *(const intx4*)(abase + o);
            m1 = *(const intx4*)(abase + o + 4);
            d0 = *(const fx4*)(dbase + o);
            d1 = *(const fx4*)(dbase + o + 4);
        }
        __syncthreads();
        // MFMA on current tile
        const short* ab = &wbuf[p][ln15 * WPAD + q * 8];
        const short* bb = bbase + it * BK;
#pragma unroll
        for (int ks = 0; ks < 4; ++ks) {
            short8 afr0 = *(const short8*)(ab + ks * 32);
            short8 afr1 = *(const short8*)(ab + 16 * WPAD + ks * 32);
            short8 bfr  = *(const short8*)(bb + ks * 32);
            acc0 = __builtin_amdgcn_mfma_f32_16x16x32_bf16(afr0, bfr, acc0, 0, 0, 0);
            acc1 = __builtin_amdgcn_mfma_f32_16x16x32_bf16(afr1, bfr, acc1, 0, 0, 0);
            if (wave == 0) {
                dac0 = __builtin_amdgcn_mfma_f32_16x16x32_bf16(afr0, ones, dac0, 0, 0, 0);
                dac1 = __builtin_amdgcn_mfma_f32_16x16x32_bf16(afr1, ones, dac1, 0, 0, 0);
            }
        }
    }

    // epilogue: atomic partial sums (4-way contention across j-chunks)
#pragma unroll
    for (int r = 0; r < 4; ++r) {
        atomicAdd(&numer[(size_t)(r0 + q * 4 + r) * OUT_F + f0 + ln15], acc0[r]);
        atomicAdd(&numer[(size_t)(r0 + 16 + q * 4 + r) * OUT_F + f0 + ln15], acc1[r]);
    }
    if (wave == 0 && ln15 == 0) {
#pragma unroll
        for (int r = 0; r < 4; ++r) {
            atomicAdd(&denom[r0 + q * 4 + r], dac0[r]);
            atomicAdd(&denom[r0 + 16 + q * 4 + r], dac1[r]);
        }
    }
}

// ---------------------------------------------------------------------------
// k_final: out = ELU(numer/denom), in place on d_out.
// ---------------------------------------------------------------------------
__global__ void k_final(float* __restrict__ out, const float* __restrict__ denom) {
    const int idx = blockIdx.x * 256 + threadIdx.x;   // grid 4096
    float v = out[idx] / denom[idx >> 7];
    v = v > 0.f ? v : (__expf(v) - 1.f);
    out[idx] = v;
}

// ---------------------------------------------------------------------------
extern "C" void kernel_launch(void* const* d_in, const int* in_sizes, int n_in,
                              void* d_out, int out_size, void* d_ws, size_t ws_size,
                              hipStream_t stream) {
    const float* h   = (const float*)d_in[0];   // fp32 [8192][256]
    const int*   adj = (const int*)d_in[1];     // int32 [8192][8192]
    const float* W   = (const float*)d_in[2];   // fp32 [256][128]
    const float* a   = (const float*)d_in[3];   // fp32 [256]
    float* out = (float*)d_out;                 // fp32 [8192][128]

    char*  ws    = (char*)d_ws;
    float* denom = (float*)ws;                                  // 32 KB
    short* WhT   = (short*)(ws + 32768);                        // 2 MB
    float* src   = (float*)(ws + 32768 + (size_t)OUT_F * N_NODES * 2);
    float* dst   = src + N_NODES;                               // 32 KB each

    k_zero <<<1032, 256, 0, stream>>>((float4*)out, (float4*)denom);
    k_wh   <<<256, 512, 0, stream>>>(h, W, a, WhT, src, dst);
    k_attn <<<1024, 512, 0, stream>>>(adj, WhT, src, dst, out, denom);
    k_final<<<4096, 256, 0, stream>>>(out, denom);
}